// Round 8
// baseline (1283.451 us; speedup 1.0000x reference)
//
#include <hip/hip_runtime.h>
#include <math.h>

constexpr int N_   = 50000;
constexpr int E_   = 800000;
constexpr int FIN_ = 32;
constexpr int D_   = 128;
constexpr int H_   = 8;
constexpr int NB_  = 5;
constexpr int L_   = 4;
constexpr int DFF_ = 512;

typedef __attribute__((ext_vector_type(8))) short short8;
typedef __attribute__((ext_vector_type(4))) short short4v;
typedef __attribute__((ext_vector_type(4))) float f32x4;

__device__ __forceinline__ short f2bf(float f){
  unsigned u = __float_as_uint(f);
  unsigned r = (u + 0x7FFFu + ((u >> 16) & 1u)) >> 16;
  return (short)r;
}
__device__ __forceinline__ float bflo(unsigned u){ return __uint_as_float(u << 16); }
__device__ __forceinline__ float bfhi(unsigned u){ return __uint_as_float(u & 0xffff0000u); }

// inline exact-gelu via A&S 7.1.26 erf (|err|<1.5e-7): no libcall, tiny live range
__device__ __forceinline__ float gelu_f(float x){
  float xs = x * 0.70710678118654752f;
  float ax = fabsf(xs);
  float t  = __builtin_amdgcn_rcpf(1.0f + 0.3275911f*ax);
  float y  = t*(0.254829592f + t*(-0.284496736f + t*(1.421413741f +
             t*(-1.453152027f + t*1.061405429f))));
  float e  = exp2f(-ax*ax*1.4426950408889634f);
  float er = 1.0f - y*e;                              // erf(|xs|)
  er = __uint_as_float((__float_as_uint(er) & 0x7fffffffu) |
                       (__float_as_uint(xs) & 0x80000000u));  // copysign
  return 0.5f*x*(1.0f + er);
}

// ---------------- weight convert + transpose to bf16 (once per call) ----------------
__global__ __launch_bounds__(256)
void conv_weights(const float* __restrict__ Wq, const float* __restrict__ Wk,
                  const float* __restrict__ Wv, const float* __restrict__ Wo,
                  const float* __restrict__ w1, const float* __restrict__ w2,
                  const float* __restrict__ ow,
                  short* __restrict__ wqkvt, short* __restrict__ wot,
                  short* __restrict__ w1t, short* __restrict__ w2t,
                  short* __restrict__ owt){
  int idx = blockIdx.x * blockDim.x + threadIdx.x;
  if (idx < 3*L_*16384){
    int m = idx / (L_*16384);
    int r = idx % (L_*16384);
    int l = r / 16384, e = r % 16384;
    int k = e >> 7, n = e & 127;
    const float* src = (m == 0) ? Wq : ((m == 1) ? Wk : Wv);
    wqkvt[(size_t)(l*3 + m)*16384 + n*128 + k] = f2bf(src[(size_t)l*16384 + e]);
    return;
  }
  idx -= 3*L_*16384;
  if (idx < L_*16384){
    int l = idx / 16384, e = idx % 16384, k = e >> 7, n = e & 127;
    wot[(size_t)l*16384 + n*128 + k] = f2bf(Wo[idx]);
    return;
  }
  idx -= L_*16384;
  if (idx < L_*D_*DFF_){            // w1: K=128 N=512 -> [n][k] ld 128
    int l = idx / 65536, e = idx % 65536;
    int k = e >> 9, n = e & 511;
    w1t[(size_t)l*65536 + n*128 + k] = f2bf(w1[idx]);
    return;
  }
  idx -= L_*D_*DFF_;
  if (idx < L_*DFF_*D_){            // w2: K=512 N=128 -> [n][k] ld 512
    int l = idx / 65536, e = idx % 65536;
    int k = e >> 7, n = e & 127;
    w2t[(size_t)l*65536 + n*512 + k] = f2bf(w2[idx]);
    return;
  }
  idx -= L_*DFF_*D_;
  if (idx < 16384){
    int k = idx >> 7, n = idx & 127;
    owt[n*128 + k] = f2bf(ow[idx]);
  }
}

// ---------------- input projection (2 nodes / block) ----------------
__global__ __launch_bounds__(256)
void input_proj(const float* __restrict__ x, const float* __restrict__ in_w,
                const float* __restrict__ in_b, const float* __restrict__ se,
                const int* __restrict__ sid, float* __restrict__ h,
                short* __restrict__ hb){
  int sub = threadIdx.x >> 7, d = threadIdx.x & 127;
  int i = blockIdx.x*2 + sub;
  __shared__ float xs[2][FIN_];
  if (d < FIN_) xs[sub][d] = x[(size_t)i*FIN_ + d];
  __syncthreads();
  float acc = in_b[d] + se[(size_t)sid[i]*D_ + d];
  #pragma unroll 8
  for (int k=0;k<FIN_;k++) acc += xs[sub][k]*in_w[k*D_+d];
  h[(size_t)i*D_+d]  = acc;
  hb[(size_t)i*D_+d] = f2bf(acc);
}

// ---------------- CSR build ----------------
__global__ void k_deg(const int* __restrict__ dst, const int* __restrict__ src,
                      const int* __restrict__ band,
                      int* __restrict__ deg, int* __restrict__ pk){
  int e = blockIdx.x*blockDim.x + threadIdx.x;
  if (e < E_){
    atomicAdd(&deg[dst[e]], 1);
    pk[e] = src[e] | (band[e] << 16);
  }
}

__global__ __launch_bounds__(1024)
void k_scan1(const int* __restrict__ deg, int* __restrict__ rowptr,
             int* __restrict__ bsum){
  __shared__ int sm[1024];
  int b = blockIdx.x, tid = threadIdx.x;
  int i = b*1024 + tid;
  int v = (i < N_) ? deg[i] : 0;
  sm[tid] = v; __syncthreads();
  for (int off=1; off<1024; off<<=1){
    int t = (tid>=off) ? sm[tid-off] : 0;
    __syncthreads();
    sm[tid] += t;
    __syncthreads();
  }
  if (i < N_) rowptr[i+1] = sm[tid];
  if (tid == 1023) bsum[b] = sm[1023];
}

__global__ void k_scan2(int* __restrict__ bsum, int nb){
  int tid = threadIdx.x;
  int v = (tid < nb) ? bsum[tid] : 0;
  for (int off=1; off<64; off<<=1){
    int t = __shfl_up(v, off, 64);
    if (tid >= off) v += t;
  }
  if (tid < nb) bsum[tid] = v;
}

__global__ void k_scan3(int* __restrict__ rowptr, const int* __restrict__ bsum){
  int i = blockIdx.x*blockDim.x + threadIdx.x;
  if (i == 0) rowptr[0] = 0;
  if (i < N_){
    int b = i >> 10;
    if (b > 0) rowptr[i+1] += bsum[b-1];
  }
}

__global__ void k_scatter(const int* __restrict__ dst, const int* __restrict__ rowptr,
                          int* __restrict__ fill, int* __restrict__ eord){
  int e = blockIdx.x*blockDim.x + threadIdx.x;
  if (e < E_){
    int d = dst[e];
    int pos = rowptr[d] + atomicAdd(&fill[d], 1);
    eord[pos] = e;
  }
}

__global__ void k_sortseg(const int* __restrict__ rowptr, int* __restrict__ eord){
  int i = blockIdx.x*blockDim.x + threadIdx.x;
  if (i >= N_) return;
  int b = rowptr[i], t = rowptr[i+1];
  for (int p = b+1; p < t; p++){
    int v = eord[p];
    int q = p-1;
    while (q >= b && eord[q] > v){ eord[q+1] = eord[q]; q--; }
    eord[q+1] = v;
  }
}

// ---------------- direct-global bf16 MFMA GEMM: C = A(Mx128) @ W(128x128) ----------------
// BM=128, 512 threads = 8 waves, wave tile 64x32 (acc[4][2]).
// EPI: 3 = bias -> f32 | 4 = no bias -> bf16 at Yb+by*cstride
template<int EPI>
__global__ __launch_bounds__(512, 2)
void gemm128_direct(const short* __restrict__ A, const short* __restrict__ Wt,
                    const float* __restrict__ bias,
                    float* Cf, short* Yb, int M, long wstride, long cstride){
  const int tid = threadIdx.x;
  const int by  = blockIdx.y;
  Wt += (size_t)by * wstride;
  short* Cb = (EPI==4) ? (Yb + (size_t)by * cstride) : Yb;
  const int m0 = blockIdx.x * 128;
  const int lane = tid & 63, w = tid >> 6;
  const int wr = w >> 2, wc = w & 3;
  const int lrow = lane & 15, lgrp = lane >> 4;
  f32x4 acc[4][2];
  #pragma unroll
  for (int r=0;r<4;r++){ acc[r][0] = {0.f,0.f,0.f,0.f}; acc[r][1] = {0.f,0.f,0.f,0.f}; }
  int rowA[4];
  #pragma unroll
  for (int r=0;r<4;r++){
    int rr = m0 + wr*64 + r*16 + lrow;
    rowA[r] = (rr < M) ? rr : (M-1);
  }
  #pragma unroll
  for (int kk = 0; kk < 4; kk++){
    const int koff = kk*32 + lgrp*8;
    short8 af[4], bfr[2];
    #pragma unroll
    for (int r = 0; r < 4; r++)
      af[r] = *(const short8*)(A + (size_t)rowA[r]*128 + koff);
    #pragma unroll
    for (int c = 0; c < 2; c++){
      int n = wc*32 + c*16 + lrow;
      bfr[c] = *(const short8*)(Wt + (size_t)n*128 + koff);
    }
    #pragma unroll
    for (int r = 0; r < 4; r++)
      #pragma unroll
      for (int c = 0; c < 2; c++)
        acc[r][c] = __builtin_amdgcn_mfma_f32_16x16x32_bf16(af[r], bfr[c], acc[r][c], 0, 0, 0);
  }
  #pragma unroll
  for (int r = 0; r < 4; r++){
    #pragma unroll
    for (int c = 0; c < 2; c++){
      int col = wc*32 + c*16 + lrow;
      float bv = (EPI == 3) ? bias[col] : 0.f;
      #pragma unroll
      for (int v = 0; v < 4; v++){
        int row = m0 + wr*64 + r*16 + lgrp*4 + v;
        if (row < M){
          float o = acc[r][c][v] + bv;
          if (EPI == 3) Cf[(size_t)row*128 + col] = o;
          else          Cb[(size_t)row*128 + col] = f2bf(o);
        }
      }
    }
  }
}

// ---------------- direct GEMM + bias + residual + LN epilogue (BM=64) ----------------
// launch_bounds (512,2): 128-VGPR cap -> no spills (empirical: arg4 caps at 64 and spills)
__global__ __launch_bounds__(512, 2)
void gemm_ln_direct(const short* __restrict__ A, const short* __restrict__ Wt,
                    const float* __restrict__ bias, const float* __restrict__ R,
                    float* Cf, short* Yb, int M,
                    const float* __restrict__ g_ln, const float* __restrict__ b_ln){
  __shared__ float tb[64*128];
  __shared__ float st[130];
  const int tid = threadIdx.x;
  const int m0 = blockIdx.x * 64;
  const int lane = tid & 63, w = tid >> 6;
  const int wr = w >> 2, wc = w & 3;
  const int lrow = lane & 15, lgrp = lane >> 4;
  f32x4 acc[2][2];
  #pragma unroll
  for (int r=0;r<2;r++){ acc[r][0] = {0.f,0.f,0.f,0.f}; acc[r][1] = {0.f,0.f,0.f,0.f}; }
  int rowA[2];
  #pragma unroll
  for (int r=0;r<2;r++){
    int rr = m0 + wr*32 + r*16 + lrow;
    rowA[r] = (rr < M) ? rr : (M-1);
  }
  #pragma unroll
  for (int kk = 0; kk < 4; kk++){
    const int koff = kk*32 + lgrp*8;
    short8 af[2], bfr[2];
    #pragma unroll
    for (int r = 0; r < 2; r++)
      af[r] = *(const short8*)(A + (size_t)rowA[r]*128 + koff);
    #pragma unroll
    for (int c = 0; c < 2; c++){
      int n = wc*32 + c*16 + lrow;
      bfr[c] = *(const short8*)(Wt + (size_t)n*128 + koff);
    }
    #pragma unroll
    for (int r = 0; r < 2; r++)
      #pragma unroll
      for (int c = 0; c < 2; c++)
        acc[r][c] = __builtin_amdgcn_mfma_f32_16x16x32_bf16(af[r], bfr[c], acc[r][c], 0, 0, 0);
  }
  #pragma unroll
  for (int r = 0; r < 2; r++){
    #pragma unroll
    for (int c = 0; c < 2; c++){
      int col = wc*32 + c*16 + lrow;
      float bv = bias[col];
      #pragma unroll
      for (int v = 0; v < 4; v++){
        int row = wr*32 + r*16 + lgrp*4 + v;
        int grow = m0 + row;
        float o = acc[r][c][v] + bv;
        if (grow < M) o += R[(size_t)grow*128 + col];
        tb[row*128 + (col ^ ((row & 31) << 2))] = o;
      }
    }
  }
  __syncthreads();
  {
    int rr = tid >> 3, oct = tid & 7;
    float sum = 0.f, sq = 0.f;
    #pragma unroll
    for (int k2 = 0; k2 < 4; k2++){
      int col4 = oct*16 + k2*4;
      f32x4 tv = *(f32x4*)&tb[rr*128 + (col4 ^ ((rr & 31) << 2))];
      sum += tv[0]+tv[1]+tv[2]+tv[3];
      sq  += tv[0]*tv[0]+tv[1]*tv[1]+tv[2]*tv[2]+tv[3]*tv[3];
    }
    sum += __shfl_xor(sum, 1); sum += __shfl_xor(sum, 2); sum += __shfl_xor(sum, 4);
    sq  += __shfl_xor(sq, 1);  sq  += __shfl_xor(sq, 2);  sq  += __shfl_xor(sq, 4);
    if (oct == 0){
      float mean = sum * (1.f/128.f);
      float var  = sq * (1.f/128.f) - mean*mean;
      st[rr*2]   = mean;
      st[rr*2+1] = rsqrtf(var + 1e-5f);
    }
  }
  __syncthreads();
  #pragma unroll
  for (int it = 0; it < 4; it++){
    int i = it*512 + tid;
    int row = i >> 5, cg = i & 31;
    int grow = m0 + row;
    if (grow < M){
      int col4 = cg*4;
      f32x4 tv = *(f32x4*)&tb[row*128 + (col4 ^ ((row & 31) << 2))];
      float mean = st[row*2], rstd = st[row*2+1];
      f32x4 gv = *(const f32x4*)(g_ln + col4);
      f32x4 bv = *(const f32x4*)(b_ln + col4);
      f32x4 y;
      short4v p;
      #pragma unroll
      for (int j = 0; j < 4; j++){
        y[j] = (tv[j] - mean) * rstd * gv[j] + bv[j];
        p[j] = f2bf(y[j]);
      }
      *(f32x4*)(Cf + (size_t)grow*128 + col4) = y;
      *(short4v*)(Yb + (size_t)grow*128 + col4) = p;
    }
  }
}

// ---------------- fused FFN (BM=64): h,hb = LN2( gelu(hb@W1+b1)@W2 + b2 + h ) ----------
// launch_bounds (512,2): 128-VGPR cap fits the ~100-reg peak -> no scratch spills.
__global__ __launch_bounds__(512, 2)
void ffn_fused(const short* __restrict__ hb, const float* __restrict__ hres,
               const short* __restrict__ w1t, const float* __restrict__ b1,
               const short* __restrict__ w2t, const float* __restrict__ b2,
               const float* __restrict__ g2, const float* __restrict__ bl2,
               float* hout, short* hbout, int M){
  __shared__ char smem[32768];
  __shared__ float st[130];
  const int tid = threadIdx.x;
  const int m0 = blockIdx.x * 64;
  const int lane = tid & 63, w = tid >> 6;
  const int lrow = lane & 15, lgrp = lane >> 4;
  const int wr2 = w >> 2, wc2 = w & 3;        // FFN2/LN tile coords
  f32x4 acc2[2][2];
  #pragma unroll
  for (int r=0;r<2;r++){ acc2[r][0] = {0.f,0.f,0.f,0.f}; acc2[r][1] = {0.f,0.f,0.f,0.f}; }
  int rowA[4];
  #pragma unroll
  for (int r=0;r<4;r++){
    int rr = m0 + r*16 + lrow;
    rowA[r] = (rr < M) ? rr : (M-1);
  }
  #pragma unroll
  for (int chunk = 0; chunk < 2; chunk++){
    // FFN1: hidden cols [chunk*256, +256); wave w owns 32 cols -> acc1[4][2]
    f32x4 acc1[4][2];
    #pragma unroll
    for (int r=0;r<4;r++){ acc1[r][0] = {0.f,0.f,0.f,0.f}; acc1[r][1] = {0.f,0.f,0.f,0.f}; }
    #pragma unroll
    for (int kk = 0; kk < 4; kk++){
      const int koff = kk*32 + lgrp*8;
      short8 af[4], bfr[2];
      #pragma unroll
      for (int r = 0; r < 4; r++)
        af[r] = *(const short8*)(hb + (size_t)rowA[r]*128 + koff);
      #pragma unroll
      for (int c = 0; c < 2; c++){
        int n1 = chunk*256 + w*32 + c*16 + lrow;
        bfr[c] = *(const short8*)(w1t + (size_t)n1*128 + koff);
      }
      #pragma unroll
      for (int r = 0; r < 4; r++)
        #pragma unroll
        for (int c = 0; c < 2; c++)
          acc1[r][c] = __builtin_amdgcn_mfma_f32_16x16x32_bf16(af[r], bfr[c], acc1[r][c], 0, 0, 0);
    }
    __syncthreads();                     // prev chunk's FFN2 LDS reads done
    // gelu -> bf16 -> LDS hidden [64][256], byte-XOR swizzle ((row&7)<<4)
    #pragma unroll
    for (int r = 0; r < 4; r++){
      #pragma unroll
      for (int c = 0; c < 2; c++){
        int nc = w*32 + c*16 + lrow;
        float bv = b1[chunk*256 + nc];
        #pragma unroll
        for (int v = 0; v < 4; v++){
          int row = r*16 + lgrp*4 + v;
          float g = gelu_f(acc1[r][c][v] + bv);
          int off = row*512 + nc*2;
          *(short*)(smem + (off ^ ((row & 7) << 4))) = f2bf(g);
        }
      }
    }
    __syncthreads();
    // FFN2 partial: acc2 += hidden(64x256) @ W2[chunk*256:+256, :]; wave tile 32x32
    #pragma unroll
    for (int kk2 = 0; kk2 < 8; kk2++){
      short8 ah[2], bh[2];
      #pragma unroll
      for (int r = 0; r < 2; r++){
        int row = wr2*32 + r*16 + lrow;
        ah[r] = *(const short8*)(smem + ((row*512 + kk2*64 + lgrp*16) ^ ((row & 7) << 4)));
      }
      #pragma unroll
      for (int c = 0; c < 2; c++){
        int n2 = wc2*32 + c*16 + lrow;
        bh[c] = *(const short8*)(w2t + (size_t)n2*512 + chunk*256 + kk2*32 + lgrp*8);
      }
      #pragma unroll
      for (int r = 0; r < 2; r++)
        #pragma unroll
        for (int c = 0; c < 2; c++)
          acc2[r][c] = __builtin_amdgcn_mfma_f32_16x16x32_bf16(ah[r], bh[c], acc2[r][c], 0, 0, 0);
    }
  }
  __syncthreads();                       // all FFN2 LDS reads done before tb overwrite
  // bias + residual -> tb (f32 64x128, swizzled), then LN2
  float* tb = (float*)smem;
  #pragma unroll
  for (int r = 0; r < 2; r++){
    #pragma unroll
    for (int c = 0; c < 2; c++){
      int col = wc2*32 + c*16 + lrow;
      float bv = b2[col];
      #pragma unroll
      for (int v = 0; v < 4; v++){
        int row = wr2*32 + r*16 + lgrp*4 + v;
        int grow = m0 + row;
        float o = acc2[r][c][v] + bv;
        if (grow < M) o += hres[(size_t)grow*128 + col];
        tb[row*128 + (col ^ ((row & 31) << 2))] = o;
      }
    }
  }
  __syncthreads();
  {
    int rr = tid >> 3, oct = tid & 7;
    float sum = 0.f, sq = 0.f;
    #pragma unroll
    for (int k2 = 0; k2 < 4; k2++){
      int col4 = oct*16 + k2*4;
      f32x4 tv = *(f32x4*)&tb[rr*128 + (col4 ^ ((rr & 31) << 2))];
      sum += tv[0]+tv[1]+tv[2]+tv[3];
      sq  += tv[0]*tv[0]+tv[1]*tv[1]+tv[2]*tv[2]+tv[3]*tv[3];
    }
    sum += __shfl_xor(sum, 1); sum += __shfl_xor(sum, 2); sum += __shfl_xor(sum, 4);
    sq  += __shfl_xor(sq, 1);  sq  += __shfl_xor(sq, 2);  sq  += __shfl_xor(sq, 4);
    if (oct == 0){
      float mean = sum * (1.f/128.f);
      float var  = sq * (1.f/128.f) - mean*mean;
      st[rr*2]   = mean;
      st[rr*2+1] = rsqrtf(var + 1e-5f);
    }
  }
  __syncthreads();
  #pragma unroll
  for (int it = 0; it < 4; it++){
    int i = it*512 + tid;
    int row = i >> 5, cg = i & 31;
    int grow = m0 + row;
    if (grow < M){
      int col4 = cg*4;
      f32x4 tv = *(f32x4*)&tb[row*128 + (col4 ^ ((row & 31) << 2))];
      float mean = st[row*2], rstd = st[row*2+1];
      f32x4 gv = *(const f32x4*)(g2 + col4);
      f32x4 bv = *(const f32x4*)(bl2 + col4);
      f32x4 y;
      short4v p;
      #pragma unroll
      for (int j = 0; j < 4; j++){
        y[j] = (tv[j] - mean) * rstd * gv[j] + bv[j];
        p[j] = f2bf(y[j]);
      }
      *(f32x4*)(hout + (size_t)grow*128 + col4) = y;
      *(short4v*)(hbout + (size_t)grow*128 + col4) = p;
    }
  }
}

// ---------------- fused per-node attention: 1 wave/node, 4 chains, fixed-max softmax ----
// Wave-uniform values (p0/p1, eord, pk, eattr) hoisted to SGPRs via readfirstlane:
// K/V gathers become saddr-form, meta chain moves to the scalar pipe.
__global__ __launch_bounds__(256, 4)
void attn_fused(const short* __restrict__ Qb, const short* __restrict__ Kb,
                const short* __restrict__ Vb, const int* __restrict__ pk,
                const float* __restrict__ eattr,
                const int* __restrict__ rowptr, const int* __restrict__ eord,
                const float* __restrict__ bb_l, short* __restrict__ aggb){
  const int lane = threadIdx.x & 63;
  const int i = (blockIdx.x << 2) + (threadIdx.x >> 6);
  if (i >= N_) return;
  const int hh = lane >> 3;
  const unsigned qw = ((const unsigned*)Qb)[(size_t)i*64 + lane];
  const float q0 = bflo(qw), q1 = bfhi(qw);
  const int p0 = __builtin_amdgcn_readfirstlane(rowptr[i]);
  const int p1 = __builtin_amdgcn_readfirstlane(rowptr[i+1]);
  constexpr float L2E = 1.442695040888963f;
  float2 outv = {0.f, 0.f};
  if (p0 < p1){
    const unsigned* Ku = (const unsigned*)Kb;
    const unsigned* Vu = (const unsigned*)Vb;
    float s[4]; float2 acc[4];
    #pragma unroll
    for (int c=0;c<4;c++){ s[c]=0.f; acc[c].x=0.f; acc[c].y=0.f; }
    int sj[4], sjN[4];
    float bb[4], ea[4], bbN[4], eaN[4];
    unsigned kw[4], vw[4], kwN[4], vwN[4];

    auto ldmeta = [&](int gb, int* SJ, float* BB, float* EA){
      #pragma unroll
      for (int c = 0; c < 4; c++){
        int idx = gb + c; idx = (idx < p1) ? idx : (p1 - 1);
        int e = __builtin_amdgcn_readfirstlane(eord[idx]);
        unsigned u = (unsigned)__builtin_amdgcn_readfirstlane(pk[e]);
        SJ[c] = (int)(u & 0xFFFFu);
        BB[c] = bb_l[(u >> 16)*H_ + hh];
        EA[c] = __uint_as_float(
                  (unsigned)__builtin_amdgcn_readfirstlane(
                      (int)__float_as_uint(eattr[e])));
      }
    };

    ldmeta(p0, sj, bb, ea);
    #pragma unroll
    for (int c = 0; c < 4; c++){
      kw[c] = Ku[(size_t)sj[c]*64 + lane];
      vw[c] = Vu[(size_t)sj[c]*64 + lane];
    }
    ldmeta(p0 + 4, sjN, bbN, eaN);

    for (int base = p0; base < p1; base += 4){
      #pragma unroll
      for (int c = 0; c < 4; c++){
        kwN[c] = Ku[(size_t)sjN[c]*64 + lane];
        vwN[c] = Vu[(size_t)sjN[c]*64 + lane];
      }
      int sj2[4]; float bb2[4], ea2[4];
      ldmeta(base + 8, sj2, bb2, ea2);
      #pragma unroll
      for (int c = 0; c < 4; c++){
        float k0 = bflo(kw[c]), k1 = bfhi(kw[c]);
        float dot = q0*k0 + q1*k1;
        dot += __shfl_xor(dot, 1, 8);
        dot += __shfl_xor(dot, 2, 8);
        dot += __shfl_xor(dot, 4, 8);
        float logit = (dot*0.25f + bb[c]) * ea[c];
        logit = fminf(logit, 60.f);
        if (base + c >= p1) logit = -1.0e30f;   // tail slot -> weight 0
        float wgt = exp2f(logit * L2E);
        float v0 = bflo(vw[c]), v1 = bfhi(vw[c]);
        s[c]     += wgt;
        acc[c].x += wgt*v0;
        acc[c].y += wgt*v1;
      }
      #pragma unroll
      for (int c = 0; c < 4; c++){
        kw[c]=kwN[c]; vw[c]=vwN[c];
        sj[c]=sjN[c]; bb[c]=bbN[c]; ea[c]=eaN[c];
        sjN[c]=sj2[c]; bbN[c]=bb2[c]; eaN[c]=ea2[c];
      }
    }
    float S = (s[0]+s[1]) + (s[2]+s[3]);
    float Ax = (acc[0].x+acc[1].x) + (acc[2].x+acc[3].x);
    float Ay = (acc[0].y+acc[1].y) + (acc[2].y+acc[3].y);
    float inv = 1.0f / (S + 1e-16f);
    outv.x = Ax * inv;
    outv.y = Ay * inv;
  }
  unsigned lo = (unsigned)(unsigned short)f2bf(outv.x);
  unsigned hi = (unsigned)(unsigned short)f2bf(outv.y);
  ((unsigned*)aggb)[(size_t)i*64 + lane] = lo | (hi << 16);
}

extern "C" void kernel_launch(void* const* d_in, const int* in_sizes, int n_in,
                              void* d_out, int out_size, void* d_ws, size_t ws_size,
                              hipStream_t stream) {
  const float* x         = (const float*)d_in[0];
  const int*   edge_index= (const int*)  d_in[1];
  const float* edge_attr = (const float*)d_in[2];
  const int*   band_ids  = (const int*)  d_in[3];
  const int*   stage_ids = (const int*)  d_in[4];
  const float* stage_emb = (const float*)d_in[5];
  const float* in_w      = (const float*)d_in[6];
  const float* in_b      = (const float*)d_in[7];
  const float* Wq        = (const float*)d_in[8];
  const float* Wk        = (const float*)d_in[9];
  const float* Wv        = (const float*)d_in[10];
  const float* Wo        = (const float*)d_in[11];
  const float* Wo_b      = (const float*)d_in[12];
  const float* band_bias = (const float*)d_in[13];
  const float* ln1_g     = (const float*)d_in[14];
  const float* ln1_b     = (const float*)d_in[15];
  const float* ffn_w1    = (const float*)d_in[16];
  const float* ffn_b1    = (const float*)d_in[17];
  const float* ffn_w2    = (const float*)d_in[18];
  const float* ffn_b2    = (const float*)d_in[19];
  const float* ln2_g     = (const float*)d_in[20];
  const float* ln2_b     = (const float*)d_in[21];
  const float* out_w     = (const float*)d_in[22];
  const float* out_b     = (const float*)d_in[23];
  float* out = (float*)d_out;

  const size_t ND = (size_t)N_*D_;           // 6.4M
  float* ws  = (float*)d_ws;
  float* h    = ws;                          // f32 N x 128
  short* qkvb = (short*)(ws + ND);           // bf16 Q,K,V (3*ND shorts)
  short* hb   = (short*)(ws + ND + 3*ND/2);  // bf16 N x 128
  short* aggb = (short*)(ws + 3*ND);         // bf16 N x 128
  short* wbuf = (short*)(ws + 3*ND + ND/2);  // bf16 weights: 802816 shorts
  short* wqkvt = wbuf;
  short* wot   = wbuf + 196608;
  short* w1t   = wbuf + 262144;
  short* w2t   = wbuf + 524288;
  short* owt   = wbuf + 786432;
  int*  ibase = (int*)(ws + 3*ND + ND/2 + 401408);
  int*  deg   = ibase;                       // N
  int*  fill  = ibase + N_;                  // N
  int*  rowptr= ibase + 2*N_;                // N+1
  int*  eord  = ibase + 3*N_ + 1;            // E
  int*  bsum  = ibase + 3*N_ + 1 + E_;       // 64
  int*  pk    = ibase + 3*N_ + 1 + E_ + 64;  // E

  const int* srcA = edge_index;
  const int* dstA = edge_index + E_;

  hipMemsetAsync(deg, 0, 2ull*N_*sizeof(int), stream);

  conv_weights<<<3136, 256, 0, stream>>>(Wq, Wk, Wv, Wo, ffn_w1, ffn_w2, out_w,
                                         wqkvt, wot, w1t, w2t, owt);
  input_proj<<<N_/2, 256, 0, stream>>>(x, in_w, in_b, stage_emb, stage_ids, h, hb);

  k_deg   <<<(E_+255)/256, 256, 0, stream>>>(dstA, srcA, band_ids, deg, pk);
  k_scan1 <<<49, 1024, 0, stream>>>(deg, rowptr, bsum);
  k_scan2 <<<1, 64, 0, stream>>>(bsum, 49);
  k_scan3 <<<(N_+255)/256, 256, 0, stream>>>(rowptr, bsum);
  k_scatter<<<(E_+255)/256, 256, 0, stream>>>(dstA, rowptr, fill, eord);
  k_sortseg<<<(N_+255)/256, 256, 0, stream>>>(rowptr, eord);

  const int GB  = (N_ + 127) / 128;          // 391
  const int GB2 = (N_ + 63) / 64;            // 782
  const int AB  = (N_ + 3) / 4;              // 12500

  for (int l = 0; l < L_; l++){
    // Q,K,V bf16 in one launch (grid.y = matrix)
    gemm128_direct<4><<<dim3(GB,3), 512, 0, stream>>>(
        hb, wqkvt + (size_t)l*3*16384, nullptr, nullptr, qkvb, N_, 16384L, (long)ND);

    attn_fused<<<AB, 256, 0, stream>>>(qkvb, qkvb + ND, qkvb + 2*ND, pk, edge_attr,
                                       rowptr, eord, band_bias + l*NB_*H_, aggb);

    // h,hb = LN1(aggb @ Wo + Wo_b + h)
    gemm_ln_direct<<<GB2, 512, 0, stream>>>(
        aggb, wot + (size_t)l*16384, Wo_b + l*D_, h, h, hb,
        N_, ln1_g + l*D_, ln1_b + l*D_);

    // h,hb = LN2(gelu(hb@W1+b1)@W2 + b2 + h)
    ffn_fused<<<GB2, 512, 0, stream>>>(
        hb, h, w1t + (size_t)l*65536, ffn_b1 + l*DFF_,
        w2t + (size_t)l*65536, ffn_b2 + l*D_,
        ln2_g + l*D_, ln2_b + l*D_, h, hb, N_);
  }

  gemm128_direct<3><<<GB, 512, 0, stream>>>(
      hb, owt, out_b, out, nullptr, N_, 0L, 0L);
}

// Round 9
// 1271.188 us; speedup vs baseline: 1.0096x; 1.0096x over previous
//
#include <hip/hip_runtime.h>
#include <math.h>

constexpr int N_   = 50000;
constexpr int E_   = 800000;
constexpr int FIN_ = 32;
constexpr int D_   = 128;
constexpr int H_   = 8;
constexpr int NB_  = 5;
constexpr int L_   = 4;
constexpr int DFF_ = 512;

typedef __attribute__((ext_vector_type(8))) short short8;
typedef __attribute__((ext_vector_type(4))) short short4v;
typedef __attribute__((ext_vector_type(4))) float f32x4;

__device__ __forceinline__ short f2bf(float f){
  unsigned u = __float_as_uint(f);
  unsigned r = (u + 0x7FFFu + ((u >> 16) & 1u)) >> 16;
  return (short)r;
}
__device__ __forceinline__ float bflo(unsigned u){ return __uint_as_float(u << 16); }
__device__ __forceinline__ float bfhi(unsigned u){ return __uint_as_float(u & 0xffff0000u); }

// inline exact-gelu via A&S 7.1.26 erf (|err|<1.5e-7): no libcall, tiny live range
__device__ __forceinline__ float gelu_f(float x){
  float xs = x * 0.70710678118654752f;
  float ax = fabsf(xs);
  float t  = __builtin_amdgcn_rcpf(1.0f + 0.3275911f*ax);
  float y  = t*(0.254829592f + t*(-0.284496736f + t*(1.421413741f +
             t*(-1.453152027f + t*1.061405429f))));
  float e  = exp2f(-ax*ax*1.4426950408889634f);
  float er = 1.0f - y*e;                              // erf(|xs|)
  er = __uint_as_float((__float_as_uint(er) & 0x7fffffffu) |
                       (__float_as_uint(xs) & 0x80000000u));  // copysign
  return 0.5f*x*(1.0f + er);
}

// ---------------- weight convert + transpose to bf16 (once per call) ----------------
__global__ __launch_bounds__(256)
void conv_weights(const float* __restrict__ Wq, const float* __restrict__ Wk,
                  const float* __restrict__ Wv, const float* __restrict__ Wo,
                  const float* __restrict__ w1, const float* __restrict__ w2,
                  const float* __restrict__ ow,
                  short* __restrict__ wqkvt, short* __restrict__ wot,
                  short* __restrict__ w1t, short* __restrict__ w2t,
                  short* __restrict__ owt){
  int idx = blockIdx.x * blockDim.x + threadIdx.x;
  if (idx < 3*L_*16384){
    int m = idx / (L_*16384);
    int r = idx % (L_*16384);
    int l = r / 16384, e = r % 16384;
    int k = e >> 7, n = e & 127;
    const float* src = (m == 0) ? Wq : ((m == 1) ? Wk : Wv);
    wqkvt[(size_t)(l*3 + m)*16384 + n*128 + k] = f2bf(src[(size_t)l*16384 + e]);
    return;
  }
  idx -= 3*L_*16384;
  if (idx < L_*16384){
    int l = idx / 16384, e = idx % 16384, k = e >> 7, n = e & 127;
    wot[(size_t)l*16384 + n*128 + k] = f2bf(Wo[idx]);
    return;
  }
  idx -= L_*16384;
  if (idx < L_*D_*DFF_){            // w1: K=128 N=512 -> [n][k] ld 128
    int l = idx / 65536, e = idx % 65536;
    int k = e >> 9, n = e & 511;
    w1t[(size_t)l*65536 + n*128 + k] = f2bf(w1[idx]);
    return;
  }
  idx -= L_*D_*DFF_;
  if (idx < L_*DFF_*D_){            // w2: K=512 N=128 -> [n][k] ld 512
    int l = idx / 65536, e = idx % 65536;
    int k = e >> 7, n = e & 127;
    w2t[(size_t)l*65536 + n*512 + k] = f2bf(w2[idx]);
    return;
  }
  idx -= L_*DFF_*D_;
  if (idx < 16384){
    int k = idx >> 7, n = idx & 127;
    owt[n*128 + k] = f2bf(ow[idx]);
  }
}

// ---------------- input projection (2 nodes / block) ----------------
__global__ __launch_bounds__(256)
void input_proj(const float* __restrict__ x, const float* __restrict__ in_w,
                const float* __restrict__ in_b, const float* __restrict__ se,
                const int* __restrict__ sid, float* __restrict__ h,
                short* __restrict__ hb){
  int sub = threadIdx.x >> 7, d = threadIdx.x & 127;
  int i = blockIdx.x*2 + sub;
  __shared__ float xs[2][FIN_];
  if (d < FIN_) xs[sub][d] = x[(size_t)i*FIN_ + d];
  __syncthreads();
  float acc = in_b[d] + se[(size_t)sid[i]*D_ + d];
  #pragma unroll 8
  for (int k=0;k<FIN_;k++) acc += xs[sub][k]*in_w[k*D_+d];
  h[(size_t)i*D_+d]  = acc;
  hb[(size_t)i*D_+d] = f2bf(acc);
}

// ---------------- CSR build ----------------
__global__ void k_deg(const int* __restrict__ dst, const int* __restrict__ src,
                      const int* __restrict__ band,
                      int* __restrict__ deg, int* __restrict__ pk){
  int e = blockIdx.x*blockDim.x + threadIdx.x;
  if (e < E_){
    atomicAdd(&deg[dst[e]], 1);
    pk[e] = src[e] | (band[e] << 16);
  }
}

__global__ __launch_bounds__(1024)
void k_scan1(const int* __restrict__ deg, int* __restrict__ rowptr,
             int* __restrict__ bsum){
  __shared__ int sm[1024];
  int b = blockIdx.x, tid = threadIdx.x;
  int i = b*1024 + tid;
  int v = (i < N_) ? deg[i] : 0;
  sm[tid] = v; __syncthreads();
  for (int off=1; off<1024; off<<=1){
    int t = (tid>=off) ? sm[tid-off] : 0;
    __syncthreads();
    sm[tid] += t;
    __syncthreads();
  }
  if (i < N_) rowptr[i+1] = sm[tid];
  if (tid == 1023) bsum[b] = sm[1023];
}

__global__ void k_scan2(int* __restrict__ bsum, int nb){
  int tid = threadIdx.x;
  int v = (tid < nb) ? bsum[tid] : 0;
  for (int off=1; off<64; off<<=1){
    int t = __shfl_up(v, off, 64);
    if (tid >= off) v += t;
  }
  if (tid < nb) bsum[tid] = v;
}

__global__ void k_scan3(int* __restrict__ rowptr, const int* __restrict__ bsum){
  int i = blockIdx.x*blockDim.x + threadIdx.x;
  if (i == 0) rowptr[0] = 0;
  if (i < N_){
    int b = i >> 10;
    if (b > 0) rowptr[i+1] += bsum[b-1];
  }
}

__global__ void k_scatter(const int* __restrict__ dst, const int* __restrict__ rowptr,
                          int* __restrict__ fill, int* __restrict__ eord){
  int e = blockIdx.x*blockDim.x + threadIdx.x;
  if (e < E_){
    int d = dst[e];
    int pos = rowptr[d] + atomicAdd(&fill[d], 1);
    eord[pos] = e;
  }
}

__global__ void k_sortseg(const int* __restrict__ rowptr, int* __restrict__ eord){
  int i = blockIdx.x*blockDim.x + threadIdx.x;
  if (i >= N_) return;
  int b = rowptr[i], t = rowptr[i+1];
  for (int p = b+1; p < t; p++){
    int v = eord[p];
    int q = p-1;
    while (q >= b && eord[q] > v){ eord[q+1] = eord[q]; q--; }
    eord[q+1] = v;
  }
}

// ---------------- direct-global bf16 MFMA GEMM: C = A(Mx128) @ W(128x128) ----------------
// BM=32, 256 threads = 4 waves, wave tile 32x32 (acc[2][2]). 8 blocks/CU target.
// EPI: 3 = bias -> f32 | 4 = no bias -> bf16 at Yb+by*cstride
template<int EPI>
__global__ __launch_bounds__(256, 8)
void gemm32_direct(const short* __restrict__ A, const short* __restrict__ Wt,
                   const float* __restrict__ bias,
                   float* Cf, short* Yb, int M, long wstride, long cstride){
  const int tid = threadIdx.x;
  const int by  = blockIdx.y;
  Wt += (size_t)by * wstride;
  short* Cb = (EPI==4) ? (Yb + (size_t)by * cstride) : Yb;
  const int m0 = blockIdx.x * 32;
  const int lane = tid & 63, w = tid >> 6;
  const int lrow = lane & 15, lgrp = lane >> 4;
  f32x4 acc[2][2];
  #pragma unroll
  for (int r=0;r<2;r++){ acc[r][0] = {0.f,0.f,0.f,0.f}; acc[r][1] = {0.f,0.f,0.f,0.f}; }
  int rowA[2];
  #pragma unroll
  for (int r=0;r<2;r++){
    int rr = m0 + r*16 + lrow;
    rowA[r] = (rr < M) ? rr : (M-1);
  }
  #pragma unroll
  for (int kk = 0; kk < 4; kk++){
    const int koff = kk*32 + lgrp*8;
    short8 af[2], bfr[2];
    #pragma unroll
    for (int r = 0; r < 2; r++)
      af[r] = *(const short8*)(A + (size_t)rowA[r]*128 + koff);
    #pragma unroll
    for (int c = 0; c < 2; c++){
      int n = w*32 + c*16 + lrow;
      bfr[c] = *(const short8*)(Wt + (size_t)n*128 + koff);
    }
    #pragma unroll
    for (int r = 0; r < 2; r++)
      #pragma unroll
      for (int c = 0; c < 2; c++)
        acc[r][c] = __builtin_amdgcn_mfma_f32_16x16x32_bf16(af[r], bfr[c], acc[r][c], 0, 0, 0);
  }
  #pragma unroll
  for (int r = 0; r < 2; r++){
    #pragma unroll
    for (int c = 0; c < 2; c++){
      int col = w*32 + c*16 + lrow;
      float bv = (EPI == 3) ? bias[col] : 0.f;
      #pragma unroll
      for (int v = 0; v < 4; v++){
        int row = m0 + r*16 + lgrp*4 + v;
        if (row < M){
          float o = acc[r][c][v] + bv;
          if (EPI == 3) Cf[(size_t)row*128 + col] = o;
          else          Cb[(size_t)row*128 + col] = f2bf(o);
        }
      }
    }
  }
}

// ---------------- direct GEMM + bias + residual + LN epilogue (BM=64, 8 waves) --------
// (512,4): 64-VGPR cap fits the small acc footprint (r6/r7-verified, no spills)
__global__ __launch_bounds__(512, 4)
void gemm_ln_direct(const short* __restrict__ A, const short* __restrict__ Wt,
                    const float* __restrict__ bias, const float* __restrict__ R,
                    float* Cf, short* Yb, int M,
                    const float* __restrict__ g_ln, const float* __restrict__ b_ln){
  __shared__ float tb[64*128];
  __shared__ float st[130];
  const int tid = threadIdx.x;
  const int m0 = blockIdx.x * 64;
  const int lane = tid & 63, w = tid >> 6;
  const int wr = w >> 2, wc = w & 3;
  const int lrow = lane & 15, lgrp = lane >> 4;
  f32x4 acc[2][2];
  #pragma unroll
  for (int r=0;r<2;r++){ acc[r][0] = {0.f,0.f,0.f,0.f}; acc[r][1] = {0.f,0.f,0.f,0.f}; }
  int rowA[2];
  #pragma unroll
  for (int r=0;r<2;r++){
    int rr = m0 + wr*32 + r*16 + lrow;
    rowA[r] = (rr < M) ? rr : (M-1);
  }
  #pragma unroll
  for (int kk = 0; kk < 4; kk++){
    const int koff = kk*32 + lgrp*8;
    short8 af[2], bfr[2];
    #pragma unroll
    for (int r = 0; r < 2; r++)
      af[r] = *(const short8*)(A + (size_t)rowA[r]*128 + koff);
    #pragma unroll
    for (int c = 0; c < 2; c++){
      int n = wc*32 + c*16 + lrow;
      bfr[c] = *(const short8*)(Wt + (size_t)n*128 + koff);
    }
    #pragma unroll
    for (int r = 0; r < 2; r++)
      #pragma unroll
      for (int c = 0; c < 2; c++)
        acc[r][c] = __builtin_amdgcn_mfma_f32_16x16x32_bf16(af[r], bfr[c], acc[r][c], 0, 0, 0);
  }
  #pragma unroll
  for (int r = 0; r < 2; r++){
    #pragma unroll
    for (int c = 0; c < 2; c++){
      int col = wc*32 + c*16 + lrow;
      float bv = bias[col];
      #pragma unroll
      for (int v = 0; v < 4; v++){
        int row = wr*32 + r*16 + lgrp*4 + v;
        int grow = m0 + row;
        float o = acc[r][c][v] + bv;
        if (grow < M) o += R[(size_t)grow*128 + col];
        tb[row*128 + (col ^ ((row & 31) << 2))] = o;
      }
    }
  }
  __syncthreads();
  {
    int rr = tid >> 3, oct = tid & 7;
    float sum = 0.f, sq = 0.f;
    #pragma unroll
    for (int k2 = 0; k2 < 4; k2++){
      int col4 = oct*16 + k2*4;
      f32x4 tv = *(f32x4*)&tb[rr*128 + (col4 ^ ((rr & 31) << 2))];
      sum += tv[0]+tv[1]+tv[2]+tv[3];
      sq  += tv[0]*tv[0]+tv[1]*tv[1]+tv[2]*tv[2]+tv[3]*tv[3];
    }
    sum += __shfl_xor(sum, 1); sum += __shfl_xor(sum, 2); sum += __shfl_xor(sum, 4);
    sq  += __shfl_xor(sq, 1);  sq  += __shfl_xor(sq, 2);  sq  += __shfl_xor(sq, 4);
    if (oct == 0){
      float mean = sum * (1.f/128.f);
      float var  = sq * (1.f/128.f) - mean*mean;
      st[rr*2]   = mean;
      st[rr*2+1] = rsqrtf(var + 1e-5f);
    }
  }
  __syncthreads();
  #pragma unroll
  for (int it = 0; it < 4; it++){
    int i = it*512 + tid;
    int row = i >> 5, cg = i & 31;
    int grow = m0 + row;
    if (grow < M){
      int col4 = cg*4;
      f32x4 tv = *(f32x4*)&tb[row*128 + (col4 ^ ((row & 31) << 2))];
      float mean = st[row*2], rstd = st[row*2+1];
      f32x4 gv = *(const f32x4*)(g_ln + col4);
      f32x4 bv = *(const f32x4*)(b_ln + col4);
      f32x4 y;
      short4v p;
      #pragma unroll
      for (int j = 0; j < 4; j++){
        y[j] = (tv[j] - mean) * rstd * gv[j] + bv[j];
        p[j] = f2bf(y[j]);
      }
      *(f32x4*)(Cf + (size_t)grow*128 + col4) = y;
      *(short4v*)(Yb + (size_t)grow*128 + col4) = p;
    }
  }
}

// ---------------- fused FFN (BM=32, 4 waves): h,hb = LN2( gelu(hb@W1+b1)@W2+b2+h ) ----
// 4 hidden-chunks of 128 cols; hidden [32][128] bf16 in 8KB LDS (swizzled); LN tile
// (16KB f32) aliases it. (256,5): 102-VGPR cap, ~5 blocks/CU = 20 waves. Grid 1563.
__global__ __launch_bounds__(256, 5)
void ffn_fused(const short* __restrict__ hb, const float* __restrict__ hres,
               const short* __restrict__ w1t, const float* __restrict__ b1,
               const short* __restrict__ w2t, const float* __restrict__ b2,
               const float* __restrict__ g2, const float* __restrict__ bl2,
               float* hout, short* hbout, int M){
  __shared__ char smem[16384];
  __shared__ float st[66];
  const int tid = threadIdx.x;
  const int m0 = blockIdx.x * 32;
  const int lane = tid & 63, w = tid >> 6;
  const int lrow = lane & 15, lgrp = lane >> 4;
  f32x4 acc2[2][2];
  #pragma unroll
  for (int r=0;r<2;r++){ acc2[r][0] = {0.f,0.f,0.f,0.f}; acc2[r][1] = {0.f,0.f,0.f,0.f}; }
  int rowA[2];
  #pragma unroll
  for (int r=0;r<2;r++){
    int rr = m0 + r*16 + lrow;
    rowA[r] = (rr < M) ? rr : (M-1);
  }
  for (int cc = 0; cc < 4; cc++){
    // FFN1: hidden cols [cc*128, +128); wave w owns 32 cols -> acc1[2][2]
    f32x4 acc1[2][2];
    #pragma unroll
    for (int r=0;r<2;r++){ acc1[r][0] = {0.f,0.f,0.f,0.f}; acc1[r][1] = {0.f,0.f,0.f,0.f}; }
    #pragma unroll
    for (int kk = 0; kk < 4; kk++){
      const int koff = kk*32 + lgrp*8;
      short8 af[2], bfr[2];
      #pragma unroll
      for (int r = 0; r < 2; r++)
        af[r] = *(const short8*)(hb + (size_t)rowA[r]*128 + koff);
      #pragma unroll
      for (int c = 0; c < 2; c++){
        int n1 = cc*128 + w*32 + c*16 + lrow;
        bfr[c] = *(const short8*)(w1t + (size_t)n1*128 + koff);
      }
      #pragma unroll
      for (int r = 0; r < 2; r++)
        #pragma unroll
        for (int c = 0; c < 2; c++)
          acc1[r][c] = __builtin_amdgcn_mfma_f32_16x16x32_bf16(af[r], bfr[c], acc1[r][c], 0, 0, 0);
    }
    __syncthreads();                     // prev chunk's FFN2 LDS reads done
    // gelu -> bf16 -> LDS hidden [32][128] (row stride 256B), swizzle byte^((row&7)<<4)
    #pragma unroll
    for (int r = 0; r < 2; r++){
      #pragma unroll
      for (int c = 0; c < 2; c++){
        int lc = w*32 + c*16 + lrow;
        float bv = b1[cc*128 + lc];
        #pragma unroll
        for (int v = 0; v < 4; v++){
          int row = r*16 + lgrp*4 + v;
          float g = gelu_f(acc1[r][c][v] + bv);
          int off = row*256 + lc*2;
          *(short*)(smem + (off ^ ((row & 7) << 4))) = f2bf(g);
        }
      }
    }
    __syncthreads();
    // FFN2 partial: acc2 += hidden(32x128) @ W2[cc*128:+128, :]; wave tile 32x32
    #pragma unroll
    for (int kk2 = 0; kk2 < 4; kk2++){
      short8 ah[2], bh[2];
      #pragma unroll
      for (int r = 0; r < 2; r++){
        int row = r*16 + lrow;
        ah[r] = *(const short8*)(smem + ((row*256 + kk2*64 + lgrp*16) ^ ((row & 7) << 4)));
      }
      #pragma unroll
      for (int c = 0; c < 2; c++){
        int n2 = w*32 + c*16 + lrow;
        bh[c] = *(const short8*)(w2t + (size_t)n2*512 + cc*128 + kk2*32 + lgrp*8);
      }
      #pragma unroll
      for (int r = 0; r < 2; r++)
        #pragma unroll
        for (int c = 0; c < 2; c++)
          acc2[r][c] = __builtin_amdgcn_mfma_f32_16x16x32_bf16(ah[r], bh[c], acc2[r][c], 0, 0, 0);
    }
  }
  __syncthreads();                       // all FFN2 LDS reads done before tb overwrite
  // bias + residual -> tb (f32 32x128, swizzled), then LN2
  float* tb = (float*)smem;
  #pragma unroll
  for (int r = 0; r < 2; r++){
    #pragma unroll
    for (int c = 0; c < 2; c++){
      int col = w*32 + c*16 + lrow;
      float bv = b2[col];
      #pragma unroll
      for (int v = 0; v < 4; v++){
        int row = r*16 + lgrp*4 + v;
        int grow = m0 + row;
        float o = acc2[r][c][v] + bv;
        if (grow < M) o += hres[(size_t)grow*128 + col];
        tb[row*128 + (col ^ ((row & 31) << 2))] = o;
      }
    }
  }
  __syncthreads();
  {
    int rr = tid >> 3, oct = tid & 7;    // 32 rows x 8 threads
    float sum = 0.f, sq = 0.f;
    #pragma unroll
    for (int k2 = 0; k2 < 4; k2++){
      int col4 = oct*16 + k2*4;
      f32x4 tv = *(f32x4*)&tb[rr*128 + (col4 ^ ((rr & 31) << 2))];
      sum += tv[0]+tv[1]+tv[2]+tv[3];
      sq  += tv[0]*tv[0]+tv[1]*tv[1]+tv[2]*tv[2]+tv[3]*tv[3];
    }
    sum += __shfl_xor(sum, 1); sum += __shfl_xor(sum, 2); sum += __shfl_xor(sum, 4);
    sq  += __shfl_xor(sq, 1);  sq  += __shfl_xor(sq, 2);  sq  += __shfl_xor(sq, 4);
    if (oct == 0){
      float mean = sum * (1.f/128.f);
      float var  = sq * (1.f/128.f) - mean*mean;
      st[rr*2]   = mean;
      st[rr*2+1] = rsqrtf(var + 1e-5f);
    }
  }
  __syncthreads();
  #pragma unroll
  for (int it = 0; it < 4; it++){
    int i = it*256 + tid;
    int row = i >> 5, cg = i & 31;
    int grow = m0 + row;
    if (grow < M){
      int col4 = cg*4;
      f32x4 tv = *(f32x4*)&tb[row*128 + (col4 ^ ((row & 31) << 2))];
      float mean = st[row*2], rstd = st[row*2+1];
      f32x4 gv = *(const f32x4*)(g2 + col4);
      f32x4 bv = *(const f32x4*)(bl2 + col4);
      f32x4 y;
      short4v p;
      #pragma unroll
      for (int j = 0; j < 4; j++){
        y[j] = (tv[j] - mean) * rstd * gv[j] + bv[j];
        p[j] = f2bf(y[j]);
      }
      *(f32x4*)(hout + (size_t)grow*128 + col4) = y;
      *(short4v*)(hbout + (size_t)grow*128 + col4) = p;
    }
  }
}

// ---------------- fused per-node attention: 1 wave/node, 4 chains, fixed-max softmax ----
// (256,8): 64-VGPR cap (need ~45) -> 8 blocks/CU = 32 waves for gather-latency hiding.
__global__ __launch_bounds__(256, 8)
void attn_fused(const short* __restrict__ Qb, const short* __restrict__ Kb,
                const short* __restrict__ Vb, const int* __restrict__ pk,
                const float* __restrict__ eattr,
                const int* __restrict__ rowptr, const int* __restrict__ eord,
                const float* __restrict__ bb_l, short* __restrict__ aggb){
  const int lane = threadIdx.x & 63;
  const int i = (blockIdx.x << 2) + (threadIdx.x >> 6);
  if (i >= N_) return;
  const int hh = lane >> 3;
  const unsigned qw = ((const unsigned*)Qb)[(size_t)i*64 + lane];
  const float q0 = bflo(qw), q1 = bfhi(qw);
  const int p0 = __builtin_amdgcn_readfirstlane(rowptr[i]);
  const int p1 = __builtin_amdgcn_readfirstlane(rowptr[i+1]);
  constexpr float L2E = 1.442695040888963f;
  float2 outv = {0.f, 0.f};
  if (p0 < p1){
    const unsigned* Ku = (const unsigned*)Kb;
    const unsigned* Vu = (const unsigned*)Vb;
    float s[4]; float2 acc[4];
    #pragma unroll
    for (int c=0;c<4;c++){ s[c]=0.f; acc[c].x=0.f; acc[c].y=0.f; }
    int sj[4], sjN[4];
    float bb[4], ea[4], bbN[4], eaN[4];
    unsigned kw[4], vw[4], kwN[4], vwN[4];

    auto ldmeta = [&](int gb, int* SJ, float* BB, float* EA){
      #pragma unroll
      for (int c = 0; c < 4; c++){
        int idx = gb + c; idx = (idx < p1) ? idx : (p1 - 1);
        int e = __builtin_amdgcn_readfirstlane(eord[idx]);
        unsigned u = (unsigned)__builtin_amdgcn_readfirstlane(pk[e]);
        SJ[c] = (int)(u & 0xFFFFu);
        BB[c] = bb_l[(u >> 16)*H_ + hh];
        EA[c] = __uint_as_float(
                  (unsigned)__builtin_amdgcn_readfirstlane(
                      (int)__float_as_uint(eattr[e])));
      }
    };

    ldmeta(p0, sj, bb, ea);
    #pragma unroll
    for (int c = 0; c < 4; c++){
      kw[c] = Ku[(size_t)sj[c]*64 + lane];
      vw[c] = Vu[(size_t)sj[c]*64 + lane];
    }
    ldmeta(p0 + 4, sjN, bbN, eaN);

    for (int base = p0; base < p1; base += 4){
      #pragma unroll
      for (int c = 0; c < 4; c++){
        kwN[c] = Ku[(size_t)sjN[c]*64 + lane];
        vwN[c] = Vu[(size_t)sjN[c]*64 + lane];
      }
      int sj2[4]; float bb2[4], ea2[4];
      ldmeta(base + 8, sj2, bb2, ea2);
      #pragma unroll
      for (int c = 0; c < 4; c++){
        float k0 = bflo(kw[c]), k1 = bfhi(kw[c]);
        float dot = q0*k0 + q1*k1;
        dot += __shfl_xor(dot, 1, 8);
        dot += __shfl_xor(dot, 2, 8);
        dot += __shfl_xor(dot, 4, 8);
        float logit = (dot*0.25f + bb[c]) * ea[c];
        logit = fminf(logit, 60.f);
        if (base + c >= p1) logit = -1.0e30f;   // tail slot -> weight 0
        float wgt = exp2f(logit * L2E);
        float v0 = bflo(vw[c]), v1 = bfhi(vw[c]);
        s[c]     += wgt;
        acc[c].x += wgt*v0;
        acc[c].y += wgt*v1;
      }
      #pragma unroll
      for (int c = 0; c < 4; c++){
        kw[c]=kwN[c]; vw[c]=vwN[c];
        sj[c]=sjN[c]; bb[c]=bbN[c]; ea[c]=eaN[c];
        sjN[c]=sj2[c]; bbN[c]=bb2[c]; eaN[c]=ea2[c];
      }
    }
    float S = (s[0]+s[1]) + (s[2]+s[3]);
    float Ax = (acc[0].x+acc[1].x) + (acc[2].x+acc[3].x);
    float Ay = (acc[0].y+acc[1].y) + (acc[2].y+acc[3].y);
    float inv = 1.0f / (S + 1e-16f);
    outv.x = Ax * inv;
    outv.y = Ay * inv;
  }
  unsigned lo = (unsigned)(unsigned short)f2bf(outv.x);
  unsigned hi = (unsigned)(unsigned short)f2bf(outv.y);
  ((unsigned*)aggb)[(size_t)i*64 + lane] = lo | (hi << 16);
}

extern "C" void kernel_launch(void* const* d_in, const int* in_sizes, int n_in,
                              void* d_out, int out_size, void* d_ws, size_t ws_size,
                              hipStream_t stream) {
  const float* x         = (const float*)d_in[0];
  const int*   edge_index= (const int*)  d_in[1];
  const float* edge_attr = (const float*)d_in[2];
  const int*   band_ids  = (const int*)  d_in[3];
  const int*   stage_ids = (const int*)  d_in[4];
  const float* stage_emb = (const float*)d_in[5];
  const float* in_w      = (const float*)d_in[6];
  const float* in_b      = (const float*)d_in[7];
  const float* Wq        = (const float*)d_in[8];
  const float* Wk        = (const float*)d_in[9];
  const float* Wv        = (const float*)d_in[10];
  const float* Wo        = (const float*)d_in[11];
  const float* Wo_b      = (const float*)d_in[12];
  const float* band_bias = (const float*)d_in[13];
  const float* ln1_g     = (const float*)d_in[14];
  const float* ln1_b     = (const float*)d_in[15];
  const float* ffn_w1    = (const float*)d_in[16];
  const float* ffn_b1    = (const float*)d_in[17];
  const float* ffn_w2    = (const float*)d_in[18];
  const float* ffn_b2    = (const float*)d_in[19];
  const float* ln2_g     = (const float*)d_in[20];
  const float* ln2_b     = (const float*)d_in[21];
  const float* out_w     = (const float*)d_in[22];
  const float* out_b     = (const float*)d_in[23];
  float* out = (float*)d_out;

  const size_t ND = (size_t)N_*D_;           // 6.4M
  float* ws  = (float*)d_ws;
  float* h    = ws;                          // f32 N x 128
  short* qkvb = (short*)(ws + ND);           // bf16 Q,K,V (3*ND shorts)
  short* hb   = (short*)(ws + ND + 3*ND/2);  // bf16 N x 128
  short* aggb = (short*)(ws + 3*ND);         // bf16 N x 128
  short* wbuf = (short*)(ws + 3*ND + ND/2);  // bf16 weights: 802816 shorts
  short* wqkvt = wbuf;
  short* wot   = wbuf + 196608;
  short* w1t   = wbuf + 262144;
  short* w2t   = wbuf + 524288;
  short* owt   = wbuf + 786432;
  int*  ibase = (int*)(ws + 3*ND + ND/2 + 401408);
  int*  deg   = ibase;                       // N
  int*  fill  = ibase + N_;                  // N
  int*  rowptr= ibase + 2*N_;                // N+1
  int*  eord  = ibase + 3*N_ + 1;            // E
  int*  bsum  = ibase + 3*N_ + 1 + E_;       // 64
  int*  pk    = ibase + 3*N_ + 1 + E_ + 64;  // E

  const int* srcA = edge_index;
  const int* dstA = edge_index + E_;

  hipMemsetAsync(deg, 0, 2ull*N_*sizeof(int), stream);

  conv_weights<<<3136, 256, 0, stream>>>(Wq, Wk, Wv, Wo, ffn_w1, ffn_w2, out_w,
                                         wqkvt, wot, w1t, w2t, owt);
  input_proj<<<N_/2, 256, 0, stream>>>(x, in_w, in_b, stage_emb, stage_ids, h, hb);

  k_deg   <<<(E_+255)/256, 256, 0, stream>>>(dstA, srcA, band_ids, deg, pk);
  k_scan1 <<<49, 1024, 0, stream>>>(deg, rowptr, bsum);
  k_scan2 <<<1, 64, 0, stream>>>(bsum, 49);
  k_scan3 <<<(N_+255)/256, 256, 0, stream>>>(rowptr, bsum);
  k_scatter<<<(E_+255)/256, 256, 0, stream>>>(dstA, rowptr, fill, eord);
  k_sortseg<<<(N_+255)/256, 256, 0, stream>>>(rowptr, eord);

  const int GB2 = (N_ + 63) / 64;            // 782
  const int GB3 = (N_ + 31) / 32;            // 1563
  const int AB  = (N_ + 3) / 4;              // 12500

  for (int l = 0; l < L_; l++){
    // Q,K,V bf16 in one launch (grid.y = matrix)
    gemm32_direct<4><<<dim3(GB3,3), 256, 0, stream>>>(
        hb, wqkvt + (size_t)l*3*16384, nullptr, nullptr, qkvb, N_, 16384L, (long)ND);

    attn_fused<<<AB, 256, 0, stream>>>(qkvb, qkvb + ND, qkvb + 2*ND, pk, edge_attr,
                                       rowptr, eord, band_bias + l*NB_*H_, aggb);

    // h,hb = LN1(aggb @ Wo + Wo_b + h)
    gemm_ln_direct<<<GB2, 512, 0, stream>>>(
        aggb, wot + (size_t)l*16384, Wo_b + l*D_, h, h, hb,
        N_, ln1_g + l*D_, ln1_b + l*D_);

    // h,hb = LN2(gelu(hb@W1+b1)@W2 + b2 + h)
    ffn_fused<<<GB3, 256, 0, stream>>>(
        hb, h, w1t + (size_t)l*65536, ffn_b1 + l*DFF_,
        w2t + (size_t)l*65536, ffn_b2 + l*D_,
        ln2_g + l*D_, ln2_b + l*D_, h, hb, N_);
  }

  gemm32_direct<3><<<GB3, 256, 0, stream>>>(
      hb, owt, out_b, out, nullptr, N_, 0L, 0L);
}